// Round 3
// baseline (764.948 us; speedup 1.0000x reference)
//
#include <hip/hip_runtime.h>

typedef _Float16 half8 __attribute__((ext_vector_type(8)));
typedef _Float16 half2v __attribute__((ext_vector_type(2)));
typedef float floatx4 __attribute__((ext_vector_type(4)));

#define K_IN 4096
#define N_OUT 4096
#define NGROUPS 32
#define BM 128
#define BN 128

__device__ __forceinline__ unsigned int pkcvt(float lo, float hi) {
    // v_cvt_pkrtz_f16_f32: element0 <- lo, element1 <- hi (fp16-origin fp32 -> exact)
    return __builtin_bit_cast(unsigned int, __builtin_amdgcn_cvt_pkrtz(lo, hi));
}

// ---------------- pass 1: x fp32 -> fp16, natural layout [M][K] ----------------
__global__ __launch_bounds__(256)
void cvt_x_f16(const float* __restrict__ x, _Float16* __restrict__ x16) {
    const size_t idx = ((size_t)blockIdx.x * 256 + threadIdx.x) * 8;
    const float4 a = *(const float4*)(x + idx);
    const float4 b = *(const float4*)(x + idx + 4);
    uint4 u;
    u.x = pkcvt(a.x, a.y);  u.y = pkcvt(a.z, a.w);
    u.z = pkcvt(b.x, b.y);  u.w = pkcvt(b.z, b.w);
    *(uint4*)(x16 + idx) = u;
}

// ---------------- pass 2: dequant qweight -> Wt fp16 [N][K] (transposed) -------
__global__ __launch_bounds__(256)
void dequant_wt(const int* __restrict__ qweight,  // [K/8, N]
                const int* __restrict__ qzeros,   // [G, N/8]
                const float* __restrict__ scales, // [G, N]
                _Float16* __restrict__ wt)        // [N, K]
{
    const int tid = threadIdx.x;
    const int col = blockIdx.x * 64 + (tid & 63);
    const int g   = blockIdx.y;
    const int i   = tid >> 6;

    const unsigned int zw = (unsigned int)qzeros[g * (N_OUT / 8) + (col >> 3)];
    const unsigned int z  = (zw >> ((col & 7) * 4)) & 0xFu;
    const unsigned int cb = 0x6400u + z + 1u;     // f16 bits of 1024+(z+1), exact
    const half2v c2 = __builtin_bit_cast(half2v, cb | (cb << 16));
    const float  s  = scales[g * N_OUT + col];
    const half2v s2 = __builtin_bit_cast(half2v, pkcvt(s, s));

    const int kc0 = g * 16 + i * 4;
#pragma unroll
    for (int r = 0; r < 4; ++r) {
        const unsigned int q = (unsigned int)qweight[(size_t)(kc0 + r) * N_OUT + col];
        const unsigned int r0 = (q & 0x000F000Fu)         | 0x64006400u; // (k0,k4)
        const unsigned int r1 = ((q >> 4) & 0x000F000Fu)  | 0x64006400u; // (k1,k5)
        const unsigned int r2 = ((q >> 8) & 0x000F000Fu)  | 0x64006400u; // (k2,k6)
        const unsigned int r3 = ((q >> 12) & 0x000F000Fu) | 0x64006400u; // (k3,k7)
        unsigned int p0 = __builtin_bit_cast(unsigned int,
                          (half2v)((__builtin_bit_cast(half2v, r0) - c2) * s2));
        unsigned int p1 = __builtin_bit_cast(unsigned int,
                          (half2v)((__builtin_bit_cast(half2v, r1) - c2) * s2));
        unsigned int p2 = __builtin_bit_cast(unsigned int,
                          (half2v)((__builtin_bit_cast(half2v, r2) - c2) * s2));
        unsigned int p3 = __builtin_bit_cast(unsigned int,
                          (half2v)((__builtin_bit_cast(half2v, r3) - c2) * s2));
        uint4 nat;
        nat.x = (p0 & 0xFFFFu) | (p1 << 16);          // (k0,k1)
        nat.y = (p2 & 0xFFFFu) | (p3 << 16);          // (k2,k3)
        nat.z = (p0 >> 16) | (p1 & 0xFFFF0000u);      // (k4,k5)
        nat.w = (p2 >> 16) | (p3 & 0xFFFF0000u);      // (k6,k7)
        *(uint4*)(wt + (size_t)col * K_IN + (kc0 + r) * 8) = nat;
    }
}

// ---------------- pass 3: fp16 GEMM, 2x2 wave grid, swizzled LDS --------------
// LDS tile [128][32] f16 (64 B rows), XOR swizzle chunk' = chunk ^ ((row>>1)&3)
// applied on BOTH ds_write and ds_read (reg-staged, rule 21 satisfied).
__global__ __launch_bounds__(256, 3)
void gemm_f16(const _Float16* __restrict__ x16,  // [M,K] f16
              const _Float16* __restrict__ wt,   // [N,K] f16
              const float* __restrict__ bias,    // [N] f32
              float* __restrict__ out)           // [M,N] f32
{
    __shared__ alignas(16) _Float16 As[2][BM * 32];

    const int tid  = threadIdx.x;
    const int lane = tid & 63;
    const int wave = tid >> 6;
    const int wm   = wave >> 1;       // 0..1 : M half
    const int wn   = wave & 1;        // 0..1 : N half
    const int l15  = lane & 15;
    const int l4   = lane >> 4;

    // XCD-aware remap: xcd = lin&7 owns N-panels [xcd*4, xcd*4+4), 2 hot at a time
    const int lin   = blockIdx.y * gridDim.x + blockIdx.x;   // 0..2047
    const int xcd   = lin & 7;
    const int idx   = lin >> 3;        // 0..255
    const int phase = idx >> 7;        // 0..1
    const int blockN = (xcd * 4 + phase * 2 + (idx & 1)) * BN;
    const int blockM = ((idx >> 1) & 63) * BM;

    floatx4 acc[4][4] = {};

    // ---- A staging: thread covers rows (srow, srow+64), 16B chunk sch ----
    const int srow = tid >> 2;         // 0..63
    const int sch  = tid & 3;
    const int schw = sch ^ ((srow >> 1) & 3);    // swizzled chunk
    const _Float16* xr0 = x16 + (size_t)(blockM + srow) * K_IN + sch * 8;
    const _Float16* xr1 = xr0 + (size_t)64 * K_IN;
    _Float16* lw0 = &As[0][srow * 32 + schw * 8];
    _Float16* lw1 = lw0 + 64 * 32;

    // ---- B columns: 4 per wave, straight from global ----
    int ncol[4];
    const _Float16* wp[4];
#pragma unroll
    for (int j = 0; j < 4; ++j) {
        ncol[j] = blockN + wn * 64 + j * 16 + l15;
        wp[j]   = wt + (size_t)ncol[j] * K_IN + l4 * 8;
    }

    const int rswz = (l15 >> 1) & 3;   // read-side swizzle (row>>1)&3, i-invariant

    // prologue: step-0 prefetch
    uint4 pa = *(const uint4*)(const void*)xr0;
    uint4 pb = *(const uint4*)(const void*)xr1;
    uint4 pw[4];
#pragma unroll
    for (int j = 0; j < 4; ++j) pw[j] = *(const uint4*)(const void*)wp[j];

    for (int t = 0; t < 4 * NGROUPS; ++t) {
        const int buf = t & 1;

        // stage prefetched A -> LDS[buf] (swizzled dest)
        *(uint4*)(void*)(lw0 + buf * (BM * 32)) = pa;
        *(uint4*)(void*)(lw1 + buf * (BM * 32)) = pb;

        // current-step B fragments (copy before overwriting prefetch regs)
        half8 bfrag[4];
#pragma unroll
        for (int j = 0; j < 4; ++j) bfrag[j] = __builtin_bit_cast(half8, pw[j]);

        // issue next step's global loads (in flight across barrier)
        const int t1 = (t + 1 < 4 * NGROUPS) ? t + 1 : t;
        pa = *(const uint4*)(const void*)(xr0 + t1 * 32);
        pb = *(const uint4*)(const void*)(xr1 + t1 * 32);
#pragma unroll
        for (int j = 0; j < 4; ++j)
            pw[j] = *(const uint4*)(const void*)(wp[j] + t1 * 32);

        __syncthreads();   // single barrier per step (double buffer)

        // A fragments: wave's 64 rows, swizzled chunk read
        half8 afrag[4];
#pragma unroll
        for (int i = 0; i < 4; ++i)
            afrag[i] = *(const half8*)(const void*)
                &As[buf][(wm * 64 + i * 16 + l15) * 32 + (l4 ^ rswz) * 8];

#pragma unroll
        for (int i = 0; i < 4; ++i)
#pragma unroll
            for (int j = 0; j < 4; ++j)
                acc[i][j] = __builtin_amdgcn_mfma_f32_16x16x32_f16(
                    afrag[i], bfrag[j], acc[i][j], 0, 0, 0);
    }

    // epilogue: C layout col=lane&15, row=(lane>>4)*4+reg
#pragma unroll
    for (int j = 0; j < 4; ++j) {
        const int n = ncol[j];
        const float bv = bias[n];
#pragma unroll
        for (int i = 0; i < 4; ++i) {
            const int m = blockM + wm * 64 + i * 16 + l4 * 4;
#pragma unroll
            for (int r = 0; r < 4; ++r)
                out[(size_t)(m + r) * N_OUT + n] = acc[i][j][r] + bv;
        }
    }
}

// ---------------- fallback: verified fused kernel (ws too small) --------------
__global__ __launch_bounds__(256, 2)
void gptq_gemm_fused(const float* __restrict__ x,
                     const int*   __restrict__ qweight,
                     const int*   __restrict__ qzeros,
                     const float* __restrict__ scales,
                     const float* __restrict__ bias,
                     float*       __restrict__ out)
{
#define LDA 40
    __shared__ alignas(16) _Float16 Asf[2][BM * LDA];

    const int tid  = threadIdx.x;
    const int lane = tid & 63;
    const int wave = tid >> 6;
    const int l15  = lane & 15;
    const int l4   = lane >> 4;

    const int blockN = blockIdx.x * BN;
    const int blockM = blockIdx.y * BM;

    floatx4 acc[8][2] = {};

    const int srow = tid >> 2;
    const int sch  = tid & 3;
    const float* xr0 = x + (size_t)(blockM + srow) * K_IN + sch * 8;
    const float* xr1 = xr0 + (size_t)64 * K_IN;
    _Float16* lw0 = &Asf[0][srow * LDA + sch * 8];
    _Float16* lw1 = &Asf[0][(srow + 64) * LDA + sch * 8];

    int ncol[2];
#pragma unroll
    for (int j = 0; j < 2; ++j) ncol[j] = blockN + wave * 32 + j * 16 + l15;

    unsigned int zraw[2]; float sraw[2];
#pragma unroll
    for (int j = 0; j < 2; ++j) {
        zraw[j] = (unsigned int)qzeros[ncol[j] >> 3];
        sraw[j] = scales[ncol[j]];
    }
    float4 pa0 = *(const float4*)(xr0);
    float4 pa1 = *(const float4*)(xr0 + 4);
    float4 pb0 = *(const float4*)(xr1);
    float4 pb1 = *(const float4*)(xr1 + 4);
    unsigned int pq[2];
    {
        const int* qr = qweight + (size_t)l4 * N_OUT;
#pragma unroll
        for (int j = 0; j < 2; ++j) pq[j] = (unsigned int)qr[ncol[j]];
    }

    for (int g = 0; g < NGROUPS; ++g) {
        unsigned int c2u[2], s2u[2];
#pragma unroll
        for (int j = 0; j < 2; ++j) {
            const unsigned int z  = (zraw[j] >> ((ncol[j] & 7) * 4)) & 0xFu;
            const unsigned int cb = 0x6400u + z + 1u;
            c2u[j] = cb | (cb << 16);
            s2u[j] = pkcvt(sraw[j], sraw[j]);
        }
        const int gn = (g + 1 < NGROUPS) ? g + 1 : g;
#pragma unroll
        for (int j = 0; j < 2; ++j) {
            zraw[j] = (unsigned int)qzeros[gn * (N_OUT / 8) + (ncol[j] >> 3)];
            sraw[j] = scales[gn * N_OUT + ncol[j]];
        }

#pragma unroll
        for (int kk = 0; kk < 4; ++kk) {
            const int t   = g * 4 + kk;
            const int buf = t & 1;

            uint4 ra, rb;
            ra.x = pkcvt(pa0.x, pa1.x);  ra.y = pkcvt(pa0.y, pa1.y);
            ra.z = pkcvt(pa0.z, pa1.z);  ra.w = pkcvt(pa0.w, pa1.w);
            rb.x = pkcvt(pb0.x, pb1.x);  rb.y = pkcvt(pb0.y, pb1.y);
            rb.z = pkcvt(pb0.z, pb1.z);  rb.w = pkcvt(pb0.w, pb1.w);
            *(uint4*)(void*)(lw0 + buf * (BM * LDA)) = ra;
            *(uint4*)(void*)(lw1 + buf * (BM * LDA)) = rb;

            unsigned int bq[2] = {pq[0], pq[1]};

            const int t1 = (t + 1 < 4 * NGROUPS) ? t + 1 : t;
            pa0 = *(const float4*)(xr0 + t1 * 32);
            pa1 = *(const float4*)(xr0 + t1 * 32 + 4);
            pb0 = *(const float4*)(xr1 + t1 * 32);
            pb1 = *(const float4*)(xr1 + t1 * 32 + 4);
            {
                const int* qr = qweight + (size_t)(t1 * 4 + l4) * N_OUT;
#pragma unroll
                for (int j = 0; j < 2; ++j) pq[j] = (unsigned int)qr[ncol[j]];
            }

            __syncthreads();

            half8 bfrag[2];
#pragma unroll
            for (int j = 0; j < 2; ++j) {
                const unsigned int q = bq[j];
                const unsigned int r0 = (q & 0x000F000Fu)        | 0x64006400u;
                const unsigned int r1 = ((q >> 4) & 0x000F000Fu) | 0x64006400u;
                const unsigned int r2 = ((q >> 8) & 0x000F000Fu) | 0x64006400u;
                const unsigned int r3 = ((q >> 12) & 0x000F000Fu)| 0x64006400u;
                const half2v c2 = __builtin_bit_cast(half2v, c2u[j]);
                const half2v s2 = __builtin_bit_cast(half2v, s2u[j]);
                union { unsigned int u[4]; half8 h; } pk;
                pk.u[0] = __builtin_bit_cast(unsigned int,
                          (half2v)((__builtin_bit_cast(half2v, r0) - c2) * s2));
                pk.u[1] = __builtin_bit_cast(unsigned int,
                          (half2v)((__builtin_bit_cast(half2v, r1) - c2) * s2));
                pk.u[2] = __builtin_bit_cast(unsigned int,
                          (half2v)((__builtin_bit_cast(half2v, r2) - c2) * s2));
                pk.u[3] = __builtin_bit_cast(unsigned int,
                          (half2v)((__builtin_bit_cast(half2v, r3) - c2) * s2));
                bfrag[j] = pk.h;
            }

            half8 afrag[8];
#pragma unroll
            for (int i = 0; i < 8; ++i)
                afrag[i] = *(const half8*)(const void*)
                    &Asf[buf][(i * 16 + l15) * LDA + l4 * 8];

#pragma unroll
            for (int i = 0; i < 8; ++i)
#pragma unroll
                for (int j = 0; j < 2; ++j)
                    acc[i][j] = __builtin_amdgcn_mfma_f32_16x16x32_f16(
                        afrag[i], bfrag[j], acc[i][j], 0, 0, 0);
        }
    }

#pragma unroll
    for (int j = 0; j < 2; ++j) {
        const int n = ncol[j];
        const float bv = bias[n];
#pragma unroll
        for (int i = 0; i < 8; ++i) {
            const int m = blockM + i * 16 + l4 * 4;
#pragma unroll
            for (int r = 0; r < 4; ++r)
                out[(size_t)(m + r) * N_OUT + n] = acc[i][j][r] + bv;
        }
    }
#undef LDA
}

extern "C" void kernel_launch(void* const* d_in, const int* in_sizes, int n_in,
                              void* d_out, int out_size, void* d_ws, size_t ws_size,
                              hipStream_t stream) {
    const float* x    = (const float*)d_in[0];
    const int*   qw   = (const int*)d_in[1];
    const int*   qz   = (const int*)d_in[2];
    const float* sc   = (const float*)d_in[3];
    const float* bias = (const float*)d_in[4];
    float*       out  = (float*)d_out;

    const int M = in_sizes[0] / K_IN;   // 8192

    const size_t x16_bytes = (size_t)M * K_IN * sizeof(_Float16);
    const size_t wt_bytes  = (size_t)N_OUT * K_IN * sizeof(_Float16);

    if (ws_size >= x16_bytes + wt_bytes) {
        _Float16* x16 = (_Float16*)d_ws;
        _Float16* wtp = (_Float16*)((char*)d_ws + x16_bytes);

        cvt_x_f16<<<(int)((size_t)M * K_IN / 2048), 256, 0, stream>>>(x, x16);
        dequant_wt<<<dim3(N_OUT / 64, NGROUPS), 256, 0, stream>>>(qw, qz, sc, wtp);
        gemm_f16<<<dim3(N_OUT / BN, M / BM), 256, 0, stream>>>(x16, wtp, bias, out);
    } else {
        gptq_gemm_fused<<<dim3(N_OUT / BN, M / BM), 256, 0, stream>>>(
            x, qw, qz, sc, bias, out);
    }
}

// Round 4
// 560.278 us; speedup vs baseline: 1.3653x; 1.3653x over previous
//
#include <hip/hip_runtime.h>

typedef _Float16 half8 __attribute__((ext_vector_type(8)));
typedef _Float16 half2v __attribute__((ext_vector_type(2)));
typedef float floatx4 __attribute__((ext_vector_type(4)));

#define K_IN 4096
#define N_OUT 4096
#define NGROUPS 32
#define BM 128
#define BN 128

__device__ __forceinline__ unsigned int pkcvt(float lo, float hi) {
    // v_cvt_pkrtz_f16_f32: element0 <- lo, element1 <- hi (fp16-origin fp32 -> exact)
    return __builtin_bit_cast(unsigned int, __builtin_amdgcn_cvt_pkrtz(lo, hi));
}

// async global->LDS, 16 B per lane; LDS dest = wave-uniform base + lane*16
__device__ __forceinline__ void gll16(const _Float16* g, _Float16* l) {
    __builtin_amdgcn_global_load_lds(
        (const __attribute__((address_space(1))) void*)g,
        (__attribute__((address_space(3))) void*)l, 16, 0, 0);
}

// ---------------- pass 1: x fp32 -> fp16, natural layout [M][K] ----------------
__global__ __launch_bounds__(256)
void cvt_x_f16(const float* __restrict__ x, _Float16* __restrict__ x16) {
    const size_t idx = ((size_t)blockIdx.x * 256 + threadIdx.x) * 8;
    const float4 a = *(const float4*)(x + idx);
    const float4 b = *(const float4*)(x + idx + 4);
    uint4 u;
    u.x = pkcvt(a.x, a.y);  u.y = pkcvt(a.z, a.w);
    u.z = pkcvt(b.x, b.y);  u.w = pkcvt(b.z, b.w);
    *(uint4*)(x16 + idx) = u;
}

// ---------------- pass 2: dequant qweight -> Wt fp16 [N][K] (transposed) -------
__global__ __launch_bounds__(256)
void dequant_wt(const int* __restrict__ qweight,  // [K/8, N]
                const int* __restrict__ qzeros,   // [G, N/8]
                const float* __restrict__ scales, // [G, N]
                _Float16* __restrict__ wt)        // [N, K]
{
    const int tid = threadIdx.x;
    const int col = blockIdx.x * 64 + (tid & 63);
    const int g   = blockIdx.y;
    const int i   = tid >> 6;

    const unsigned int zw = (unsigned int)qzeros[g * (N_OUT / 8) + (col >> 3)];
    const unsigned int z  = (zw >> ((col & 7) * 4)) & 0xFu;
    const unsigned int cb = 0x6400u + z + 1u;     // f16 bits of 1024+(z+1), exact
    const half2v c2 = __builtin_bit_cast(half2v, cb | (cb << 16));
    const float  s  = scales[g * N_OUT + col];
    const half2v s2 = __builtin_bit_cast(half2v, pkcvt(s, s));

    const int kc0 = g * 16 + i * 4;
#pragma unroll
    for (int r = 0; r < 4; ++r) {
        const unsigned int q = (unsigned int)qweight[(size_t)(kc0 + r) * N_OUT + col];
        const unsigned int r0 = (q & 0x000F000Fu)         | 0x64006400u; // (k0,k4)
        const unsigned int r1 = ((q >> 4) & 0x000F000Fu)  | 0x64006400u; // (k1,k5)
        const unsigned int r2 = ((q >> 8) & 0x000F000Fu)  | 0x64006400u; // (k2,k6)
        const unsigned int r3 = ((q >> 12) & 0x000F000Fu) | 0x64006400u; // (k3,k7)
        unsigned int p0 = __builtin_bit_cast(unsigned int,
                          (half2v)((__builtin_bit_cast(half2v, r0) - c2) * s2));
        unsigned int p1 = __builtin_bit_cast(unsigned int,
                          (half2v)((__builtin_bit_cast(half2v, r1) - c2) * s2));
        unsigned int p2 = __builtin_bit_cast(unsigned int,
                          (half2v)((__builtin_bit_cast(half2v, r2) - c2) * s2));
        unsigned int p3 = __builtin_bit_cast(unsigned int,
                          (half2v)((__builtin_bit_cast(half2v, r3) - c2) * s2));
        uint4 nat;
        nat.x = (p0 & 0xFFFFu) | (p1 << 16);          // (k0,k1)
        nat.y = (p2 & 0xFFFFu) | (p3 << 16);          // (k2,k3)
        nat.z = (p0 >> 16) | (p1 & 0xFFFF0000u);      // (k4,k5)
        nat.w = (p2 >> 16) | (p3 & 0xFFFF0000u);      // (k6,k7)
        *(uint4*)(wt + (size_t)col * K_IN + (kc0 + r) * 8) = nat;
    }
}

// ---------------- pass 3: fp16 GEMM, counted-vmcnt gll pipeline ---------------
// Tile 128x128, 4 waves of 128x32 (round-2 verified shape).
// A: global_load_lds -> linear LDS [128][32] f16; logical (row,chunk) stored at
//    physical chunk = chunk ^ ((row>>1)&3)  (round-3 verified: conflicts = 0).
//    gll dest is linear, so the SOURCE global address is pre-swizzled per-lane.
// B: 2 cols/wave straight from global (round-2 verified: 8 KB/block-step).
// One raw s_barrier per step, preceded by s_waitcnt vmcnt(2): the 2 newest
// loads (next-step B) stay in flight; only the gll pair publishing the buffer
// is drained. Never vmcnt(0) in the loop.
__global__ __launch_bounds__(256, 3)
void gemm_f16(const _Float16* __restrict__ x16,  // [M,K] f16
              const _Float16* __restrict__ wt,   // [N,K] f16
              const float* __restrict__ bias,    // [N] f32
              float* __restrict__ out)           // [M,N] f32
{
    __shared__ alignas(16) _Float16 As[2 * BM * 32];   // 16 KiB

    const int tid  = threadIdx.x;
    const int lane = tid & 63;
    const int wave = tid >> 6;
    const int l15  = lane & 15;
    const int l4   = lane >> 4;

    const int blockN = blockIdx.x * BN;
    const int blockM = blockIdx.y * BM;

    floatx4 acc[8][2] = {};

    // ---- gll staging geometry: wave w stages rows [w*32, w*32+32) ----
    // physical slot p = w*128 + c*64 + lane ; row = p>>2 ; logical chunk =
    // (lane&3) ^ ((lane>>3)&3)  (derivation: (row>>1)&3 == (lane>>3)&3).
    const int grow  = wave * 32 + (lane >> 2);
    const int gchnk = (lane & 3) ^ ((lane >> 3) & 3);
    const _Float16* gsrc0 = x16 + (size_t)(blockM + grow) * K_IN + gchnk * 8;
    const _Float16* gsrc1 = gsrc0 + (size_t)16 * K_IN;   // call 1: rows +16
    _Float16* ldst0 = &As[wave * 1024];                  // wave-uniform base
    _Float16* ldst1 = ldst0 + 512;

    // ---- read-side swizzle (verified r3): chunk = l4 ^ ((l15>>1)&3) ----
    const int rdoff = (l4 ^ ((l15 >> 1) & 3)) * 8;

    // ---- B columns: 2 per wave ----
    int ncol[2];
    const _Float16* wp0;
    const _Float16* wp1;
    ncol[0] = blockN + wave * 32 + l15;
    ncol[1] = ncol[0] + 16;
    wp0 = wt + (size_t)ncol[0] * K_IN + l4 * 8;
    wp1 = wt + (size_t)ncol[1] * K_IN + l4 * 8;

    // ---- prologue: stage step 0 into buf0, then B(0) ----
    gll16(gsrc0, ldst0);
    gll16(gsrc1, ldst1);
    __builtin_amdgcn_sched_barrier(0);
    uint4 pw0 = *(const uint4*)(const void*)wp0;
    uint4 pw1 = *(const uint4*)(const void*)wp1;

    for (int t = 0; t < 4 * NGROUPS; ++t) {
        const int buf = t & 1;

        // publish buf: drain our gll pair (2 newest = B just issued stay live)
        asm volatile("s_waitcnt vmcnt(2)" ::: "memory");
        __builtin_amdgcn_s_barrier();
        asm volatile("" ::: "memory");

        // A fragments from LDS[buf] (swizzled read, conflict-free)
        half8 afrag[8];
#pragma unroll
        for (int i = 0; i < 8; ++i)
            afrag[i] = *(const half8*)(const void*)
                &As[buf * 4096 + (i * 16 + l15) * 32 + rdoff];

        half8 b0 = __builtin_bit_cast(half8, pw0);
        half8 b1 = __builtin_bit_cast(half8, pw1);

        // stage t+1 into buf^1 (issued AFTER the barrier: WAR-safe vs t-1 reads)
        const int t1 = (t + 1 < 4 * NGROUPS) ? t + 1 : t;
        const int bn = buf ^ 1;
        gll16(gsrc0 + t1 * 32, ldst0 + bn * 4096);
        gll16(gsrc1 + t1 * 32, ldst1 + bn * 4096);
        __builtin_amdgcn_sched_barrier(0);   // pin order: gll pair before B pair
        pw0 = *(const uint4*)(const void*)(wp0 + t1 * 32);
        pw1 = *(const uint4*)(const void*)(wp1 + t1 * 32);

#pragma unroll
        for (int i = 0; i < 8; ++i) {
            acc[i][0] = __builtin_amdgcn_mfma_f32_16x16x32_f16(
                afrag[i], b0, acc[i][0], 0, 0, 0);
            acc[i][1] = __builtin_amdgcn_mfma_f32_16x16x32_f16(
                afrag[i], b1, acc[i][1], 0, 0, 0);
        }
    }

    // epilogue: C layout col=lane&15, row=(lane>>4)*4+reg
#pragma unroll
    for (int j = 0; j < 2; ++j) {
        const int n = ncol[j];
        const float bv = bias[n];
#pragma unroll
        for (int i = 0; i < 8; ++i) {
            const int m = blockM + i * 16 + l4 * 4;
#pragma unroll
            for (int r = 0; r < 4; ++r)
                out[(size_t)(m + r) * N_OUT + n] = acc[i][j][r] + bv;
        }
    }
}

// ---------------- fallback: verified fused kernel (ws too small) --------------
__global__ __launch_bounds__(256, 2)
void gptq_gemm_fused(const float* __restrict__ x,
                     const int*   __restrict__ qweight,
                     const int*   __restrict__ qzeros,
                     const float* __restrict__ scales,
                     const float* __restrict__ bias,
                     float*       __restrict__ out)
{
#define LDA 40
    __shared__ alignas(16) _Float16 Asf[2][BM * LDA];

    const int tid  = threadIdx.x;
    const int lane = tid & 63;
    const int wave = tid >> 6;
    const int l15  = lane & 15;
    const int l4   = lane >> 4;

    const int blockN = blockIdx.x * BN;
    const int blockM = blockIdx.y * BM;

    floatx4 acc[8][2] = {};

    const int srow = tid >> 2;
    const int sch  = tid & 3;
    const float* xr0 = x + (size_t)(blockM + srow) * K_IN + sch * 8;
    const float* xr1 = xr0 + (size_t)64 * K_IN;
    _Float16* lw0 = &Asf[0][srow * LDA + sch * 8];
    _Float16* lw1 = &Asf[0][(srow + 64) * LDA + sch * 8];

    int ncol[2];
#pragma unroll
    for (int j = 0; j < 2; ++j) ncol[j] = blockN + wave * 32 + j * 16 + l15;

    unsigned int zraw[2]; float sraw[2];
#pragma unroll
    for (int j = 0; j < 2; ++j) {
        zraw[j] = (unsigned int)qzeros[ncol[j] >> 3];
        sraw[j] = scales[ncol[j]];
    }
    float4 pa0 = *(const float4*)(xr0);
    float4 pa1 = *(const float4*)(xr0 + 4);
    float4 pb0 = *(const float4*)(xr1);
    float4 pb1 = *(const float4*)(xr1 + 4);
    unsigned int pq[2];
    {
        const int* qr = qweight + (size_t)l4 * N_OUT;
#pragma unroll
        for (int j = 0; j < 2; ++j) pq[j] = (unsigned int)qr[ncol[j]];
    }

    for (int g = 0; g < NGROUPS; ++g) {
        unsigned int c2u[2], s2u[2];
#pragma unroll
        for (int j = 0; j < 2; ++j) {
            const unsigned int z  = (zraw[j] >> ((ncol[j] & 7) * 4)) & 0xFu;
            const unsigned int cb = 0x6400u + z + 1u;
            c2u[j] = cb | (cb << 16);
            s2u[j] = pkcvt(sraw[j], sraw[j]);
        }
        const int gn = (g + 1 < NGROUPS) ? g + 1 : g;
#pragma unroll
        for (int j = 0; j < 2; ++j) {
            zraw[j] = (unsigned int)qzeros[gn * (N_OUT / 8) + (ncol[j] >> 3)];
            sraw[j] = scales[gn * N_OUT + ncol[j]];
        }

#pragma unroll
        for (int kk = 0; kk < 4; ++kk) {
            const int t   = g * 4 + kk;
            const int buf = t & 1;

            uint4 ra, rb;
            ra.x = pkcvt(pa0.x, pa1.x);  ra.y = pkcvt(pa0.y, pa1.y);
            ra.z = pkcvt(pa0.z, pa1.z);  ra.w = pkcvt(pa0.w, pa1.w);
            rb.x = pkcvt(pb0.x, pb1.x);  rb.y = pkcvt(pb0.y, pb1.y);
            rb.z = pkcvt(pb0.z, pb1.z);  rb.w = pkcvt(pb0.w, pb1.w);
            *(uint4*)(void*)(lw0 + buf * (BM * LDA)) = ra;
            *(uint4*)(void*)(lw1 + buf * (BM * LDA)) = rb;

            unsigned int bq[2] = {pq[0], pq[1]};

            const int t1 = (t + 1 < 4 * NGROUPS) ? t + 1 : t;
            pa0 = *(const float4*)(xr0 + t1 * 32);
            pa1 = *(const float4*)(xr0 + t1 * 32 + 4);
            pb0 = *(const float4*)(xr1 + t1 * 32);
            pb1 = *(const float4*)(xr1 + t1 * 32 + 4);
            {
                const int* qr = qweight + (size_t)(t1 * 4 + l4) * N_OUT;
#pragma unroll
                for (int j = 0; j < 2; ++j) pq[j] = (unsigned int)qr[ncol[j]];
            }

            __syncthreads();

            half8 bfrag[2];
#pragma unroll
            for (int j = 0; j < 2; ++j) {
                const unsigned int q = bq[j];
                const unsigned int r0 = (q & 0x000F000Fu)        | 0x64006400u;
                const unsigned int r1 = ((q >> 4) & 0x000F000Fu) | 0x64006400u;
                const unsigned int r2 = ((q >> 8) & 0x000F000Fu) | 0x64006400u;
                const unsigned int r3 = ((q >> 12) & 0x000F000Fu)| 0x64006400u;
                const half2v c2 = __builtin_bit_cast(half2v, c2u[j]);
                const half2v s2 = __builtin_bit_cast(half2v, s2u[j]);
                union { unsigned int u[4]; half8 h; } pk;
                pk.u[0] = __builtin_bit_cast(unsigned int,
                          (half2v)((__builtin_bit_cast(half2v, r0) - c2) * s2));
                pk.u[1] = __builtin_bit_cast(unsigned int,
                          (half2v)((__builtin_bit_cast(half2v, r1) - c2) * s2));
                pk.u[2] = __builtin_bit_cast(unsigned int,
                          (half2v)((__builtin_bit_cast(half2v, r2) - c2) * s2));
                pk.u[3] = __builtin_bit_cast(unsigned int,
                          (half2v)((__builtin_bit_cast(half2v, r3) - c2) * s2));
                bfrag[j] = pk.h;
            }

            half8 afrag[8];
#pragma unroll
            for (int i = 0; i < 8; ++i)
                afrag[i] = *(const half8*)(const void*)
                    &Asf[buf][(i * 16 + l15) * LDA + l4 * 8];

#pragma unroll
            for (int i = 0; i < 8; ++i)
#pragma unroll
                for (int j = 0; j < 2; ++j)
                    acc[i][j] = __builtin_amdgcn_mfma_f32_16x16x32_f16(
                        afrag[i], bfrag[j], acc[i][j], 0, 0, 0);
        }
    }

#pragma unroll
    for (int j = 0; j < 2; ++j) {
        const int n = ncol[j];
        const float bv = bias[n];
#pragma unroll
        for (int i = 0; i < 8; ++i) {
            const int m = blockM + i * 16 + l4 * 4;
#pragma unroll
            for (int r = 0; r < 4; ++r)
                out[(size_t)(m + r) * N_OUT + n] = acc[i][j][r] + bv;
        }
    }
#undef LDA
}

extern "C" void kernel_launch(void* const* d_in, const int* in_sizes, int n_in,
                              void* d_out, int out_size, void* d_ws, size_t ws_size,
                              hipStream_t stream) {
    const float* x    = (const float*)d_in[0];
    const int*   qw   = (const int*)d_in[1];
    const int*   qz   = (const int*)d_in[2];
    const float* sc   = (const float*)d_in[3];
    const float* bias = (const float*)d_in[4];
    float*       out  = (float*)d_out;

    const int M = in_sizes[0] / K_IN;   // 8192

    const size_t x16_bytes = (size_t)M * K_IN * sizeof(_Float16);
    const size_t wt_bytes  = (size_t)N_OUT * K_IN * sizeof(_Float16);

    if (ws_size >= x16_bytes + wt_bytes) {
        _Float16* x16 = (_Float16*)d_ws;
        _Float16* wtp = (_Float16*)((char*)d_ws + x16_bytes);

        cvt_x_f16<<<(int)((size_t)M * K_IN / 2048), 256, 0, stream>>>(x, x16);
        dequant_wt<<<dim3(N_OUT / 64, NGROUPS), 256, 0, stream>>>(qw, qz, sc, wtp);
        gemm_f16<<<dim3(N_OUT / BN, M / BM), 256, 0, stream>>>(x16, wtp, bias, out);
    } else {
        gptq_gemm_fused<<<dim3(N_OUT / BN, M / BM), 256, 0, stream>>>(
            x, qw, qz, sc, bias, out);
    }
}